// Round 11
// baseline (223.281 us; speedup 1.0000x reference)
//
#include <hip/hip_runtime.h>
#include <hip/hip_bf16.h>
#include <math.h>

// GNNAngle round 11: R9 structure (best, 138.9us) + grid-stride persistence at
// the SAME block shape (256 thr, 3 blocks/CU, grid=768). Each block runs ~8
// chunks; the next chunk's 16 loads issue right after the current chunk's raw
// regs are consumed, completing under phase B's MFMA+barriers. Unbundles the
// one good idea from R10's regressing mega-block.

#define NTHREADS 256    // 4 waves
#define CHUNK    32     // nodes per chunk
#define ASTRIDE  136    // f16 act row stride (b128 conflict-free in MLP)
#define PBLOCKS  768    // 3 per CU

typedef _Float16 f16;
typedef f16  f16x8 __attribute__((ext_vector_type(8)));
typedef f16  f16x4 __attribute__((ext_vector_type(4)));
typedef float f32x4 __attribute__((ext_vector_type(4)));

__device__ __forceinline__ float fast_tanh(float x) {
    float e = __expf(2.0f * x);
    return 1.0f - 2.0f * __builtin_amdgcn_rcpf(e + 1.0f);
}

__device__ __forceinline__ float fast_acos(float x) {
    // Abramowitz-Stegun 4.4.45: max abs error 6.7e-5 rad, branchless
    float ax = fabsf(x);
    float p = fmaf(-0.0187293f, ax, 0.0742610f);
    p = fmaf(p, ax, -0.2121144f);
    p = fmaf(p, ax, 1.5707288f);
    float r = sqrtf(1.0f - ax) * p;
    return (x >= 0.0f) ? r : (3.14159265358979f - r);
}

// ---- prep: W[i][j] (f32 [IN][128]) -> Wt[j][i] f16 [128][128], K zero-padded
__global__ void prep_weights(const float* __restrict__ W1,
                             const float* __restrict__ W2,
                             const float* __restrict__ W3,
                             f16* __restrict__ wt)
{
    int tid = blockIdx.x * 256 + threadIdx.x;
    if (tid >= 3 * 128 * 128) return;
    int layer = tid >> 14;
    int rem   = tid & 16383;
    int j     = rem >> 7;
    int i     = rem & 127;
    const float* W = (layer == 0) ? W1 : ((layer == 1) ? W2 : W3);
    int in_l = (layer == 0) ? 120 : 128;
    float v = (i < in_l) ? W[i * 128 + j] : 0.0f;
    wt[tid] = (f16)v;   // wt[layer][j][i]
}

// per-node Gram+acos: c0/c1 hold row lr, dims lg*8..+8; writes angles to actF row m
__device__ __forceinline__ void gram_acos_node(float4 c0, float4 c1, int m,
                                               int lr, int lg, f16* actF)
{
    float ss = c0.x*c0.x + c0.y*c0.y + c0.z*c0.z + c0.w*c0.w
             + c1.x*c1.x + c1.y*c1.y + c1.z*c1.z + c1.w*c1.w;
    ss += __shfl_xor(ss, 16);
    ss += __shfl_xor(ss, 32);
    const float sc = __builtin_amdgcn_rsqf(ss + 1e-24f);
    f16x8 frag;
    frag[0] = (f16)(c0.x * sc); frag[1] = (f16)(c0.y * sc);
    frag[2] = (f16)(c0.z * sc); frag[3] = (f16)(c0.w * sc);
    frag[4] = (f16)(c1.x * sc); frag[5] = (f16)(c1.y * sc);
    frag[6] = (f16)(c1.z * sc); frag[7] = (f16)(c1.w * sc);
    f32x4 acc = {0.f, 0.f, 0.f, 0.f};
    acc = __builtin_amdgcn_mfma_f32_16x16x32_f16(frag, frag, acc, 0, 0, 0);
    const int col = lr;
    #pragma unroll
    for (int r2 = 0; r2 < 4; ++r2) {
        const int row = lg * 4 + r2;
        float c = fminf(fmaxf(acc[r2], -1.0f + 1e-7f), 1.0f - 1e-7f);
        float ang = fast_acos(c);
        if (row < col) {
            const int p = 15 * row - ((row * (row - 1)) >> 1) + (col - row - 1);
            actF[m * ASTRIDE + p] = (f16)ang;
        }
    }
}

// one MLP layer: dst[node][j] = tanh(sum_i src[node][i]*W[i][j] + b[j])
__device__ __forceinline__ void mlp_layer_mfma(const f16* __restrict__ wl,   // [128][128] f16 ([j][i])
                                               const float* __restrict__ bias,
                                               const f16* src, f16* dst,     // LDS, stride ASTRIDE
                                               int w, int lr, int lg)
{
    #pragma unroll
    for (int jj = 0; jj < 2; ++jj) {
        const int jt = w * 2 + jj;
        const f16* wr = wl + (jt * 16 + lr) * 128 + lg * 8;
        f16x8 a0 = *(const f16x8*)(wr);
        f16x8 a1 = *(const f16x8*)(wr + 32);
        f16x8 a2 = *(const f16x8*)(wr + 64);
        f16x8 a3 = *(const f16x8*)(wr + 96);
        f32x4 bv = *(const f32x4*)(bias + jt * 16 + lg * 4);
        #pragma unroll
        for (int nt = 0; nt < 2; ++nt) {
            const int node = nt * 16 + lr;
            const f16* sr = src + node * ASTRIDE + lg * 8;
            f16x8 bf0 = *(const f16x8*)(sr);
            f16x8 bf1 = *(const f16x8*)(sr + 32);
            f16x8 bf2 = *(const f16x8*)(sr + 64);
            f16x8 bf3 = *(const f16x8*)(sr + 96);
            f32x4 acc = {0.f, 0.f, 0.f, 0.f};
            acc = __builtin_amdgcn_mfma_f32_16x16x32_f16(a0, bf0, acc, 0, 0, 0);
            acc = __builtin_amdgcn_mfma_f32_16x16x32_f16(a1, bf1, acc, 0, 0, 0);
            acc = __builtin_amdgcn_mfma_f32_16x16x32_f16(a2, bf2, acc, 0, 0, 0);
            acc = __builtin_amdgcn_mfma_f32_16x16x32_f16(a3, bf3, acc, 0, 0, 0);
            f16x4 o;
            #pragma unroll
            for (int r = 0; r < 4; ++r)
                o[r] = (f16)fast_tanh(acc[r] + bv[r]);
            *(f16x4*)(dst + node * ASTRIDE + jt * 16 + lg * 4) = o;
        }
    }
}

__global__ __launch_bounds__(NTHREADS, 3)
void gnn_persist(const float* __restrict__ edge_attr,
                 const f16*   __restrict__ wt,     // 3x[128][128] f16
                 const float* __restrict__ b1, const float* __restrict__ b2,
                 const float* __restrict__ b3,
                 const float* __restrict__ W4, const float* __restrict__ b4,
                 float* __restrict__ out, int n_nodes, int nchunks)
{
    __shared__ __attribute__((aligned(16))) f16 actA[CHUNK * ASTRIDE];
    __shared__ __attribute__((aligned(16))) f16 actB[CHUNK * ASTRIDE];

    const int t = threadIdx.x;
    const int w = t >> 6;    // wave 0..3
    const int l = t & 63;
    const int lr = l & 15;
    const int lg = l >> 4;

    // K-pad feats 120..127 for all 32 rows, ONCE (angle writes never touch them,
    // and every chunk rewrites all 120 angle slots)
    actA[(t >> 3) * ASTRIDE + 120 + (t & 7)] = (f16)0.f;

    // wave w owns nodes m = 4c + w, c = 0..7 of each chunk
    #define LOADN(da, db, c, ch)                                                \
        {                                                                       \
            const long gn = (long)(ch) * CHUNK + (c) * 4 + w;                   \
            da = make_float4(0.f,0.f,0.f,0.f); db = da;                         \
            if (gn < n_nodes) {                                                 \
                const float* s = edge_attr + gn * 512 + lr * 32 + lg * 8;       \
                da = *(const float4*)(s);                                       \
                db = *(const float4*)(s + 4);                                   \
            }                                                                   \
        }

    long chunk = blockIdx.x;
    float4 d0a,d0b,d1a,d1b,d2a,d2b,d3a,d3b,d4a,d4b,d5a,d5b,d6a,d6b,d7a,d7b;
    LOADN(d0a,d0b,0,chunk) LOADN(d1a,d1b,1,chunk)
    LOADN(d2a,d2b,2,chunk) LOADN(d3a,d3b,3,chunk)
    LOADN(d4a,d4b,4,chunk) LOADN(d5a,d5b,5,chunk)
    LOADN(d6a,d6b,6,chunk) LOADN(d7a,d7b,7,chunk)

    for (; chunk < nchunks; chunk += PBLOCKS) {
        // ---- phase A: Gram + acos from held regs -> actA ----
        gram_acos_node(d0a, d0b, w +  0, lr, lg, actA);
        gram_acos_node(d1a, d1b, w +  4, lr, lg, actA);
        gram_acos_node(d2a, d2b, w +  8, lr, lg, actA);
        gram_acos_node(d3a, d3b, w + 12, lr, lg, actA);
        gram_acos_node(d4a, d4b, w + 16, lr, lg, actA);
        gram_acos_node(d5a, d5b, w + 20, lr, lg, actA);
        gram_acos_node(d6a, d6b, w + 24, lr, lg, actA);
        gram_acos_node(d7a, d7b, w + 28, lr, lg, actA);

        // ---- issue next chunk's 16 loads; they complete under phase B ----
        const long nxt = chunk + PBLOCKS;
        float4 e0a,e0b,e1a,e1b,e2a,e2b,e3a,e3b,e4a,e4b,e5a,e5b,e6a,e6b,e7a,e7b;
        e0a=e0b=e1a=e1b=e2a=e2b=e3a=e3b=make_float4(0.f,0.f,0.f,0.f);
        e4a=e4b=e5a=e5b=e6a=e6b=e7a=e7b=e0a;
        if (nxt < nchunks) {
            LOADN(e0a,e0b,0,nxt) LOADN(e1a,e1b,1,nxt)
            LOADN(e2a,e2b,2,nxt) LOADN(e3a,e3b,3,nxt)
            LOADN(e4a,e4b,4,nxt) LOADN(e5a,e5b,5,nxt)
            LOADN(e6a,e6b,6,nxt) LOADN(e7a,e7b,7,nxt)
        }
        __syncthreads();   // actA complete (also: prev final done before actB reuse)

        // ---- phase B: MLP on MFMA ----
        mlp_layer_mfma(wt,             b1, actA, actB, w, lr, lg);
        __syncthreads();
        mlp_layer_mfma(wt + 16384,     b2, actB, actA, w, lr, lg);
        __syncthreads();
        mlp_layer_mfma(wt + 2 * 16384, b3, actA, actB, w, lr, lg);
        __syncthreads();

        // ---- final 128->1 + sigmoid: 8 threads per node ----
        {
            const int node = t >> 3;       // 0..31
            const int part = t & 7;        // 0..7
            const int i0 = part * 16;
            const f16* sr = actB + node * ASTRIDE + i0;
            f16x8 h0 = *(const f16x8*)(sr);
            f16x8 h1 = *(const f16x8*)(sr + 8);
            float s = 0.f;
            #pragma unroll
            for (int e = 0; e < 8; ++e) s = fmaf((float)h0[e], W4[i0 + e], s);
            #pragma unroll
            for (int e = 0; e < 8; ++e) s = fmaf((float)h1[e], W4[i0 + 8 + e], s);
            s += __shfl_xor(s, 1);
            s += __shfl_xor(s, 2);
            s += __shfl_xor(s, 4);
            if (part == 0) {
                const long g = chunk * CHUNK + node;
                if (g < n_nodes)
                    out[g] = __builtin_amdgcn_rcpf(1.0f + __expf(-(s + b4[0])));
            }
        }
        // no trailing barrier needed: next iteration's post-A __syncthreads
        // separates this final's actB reads from the next L1's actB writes.

        d0a=e0a; d0b=e0b; d1a=e1a; d1b=e1b; d2a=e2a; d2b=e2b; d3a=e3a; d3b=e3b;
        d4a=e4a; d4b=e4b; d5a=e5a; d5b=e5b; d6a=e6a; d6b=e6b; d7a=e7a; d7b=e7b;
    }
    #undef LOADN
}

extern "C" void kernel_launch(void* const* d_in, const int* in_sizes, int n_in,
                              void* d_out, int out_size, void* d_ws, size_t ws_size,
                              hipStream_t stream) {
    // inputs: 0:x 1:edge_index 2:edge_attr 3:k 4:W1 5:b1 6:W2 7:b2 8:W3 9:b3 10:W4 11:b4
    const float* edge_attr = (const float*)d_in[2];
    const float* W1 = (const float*)d_in[4];
    const float* b1 = (const float*)d_in[5];
    const float* W2 = (const float*)d_in[6];
    const float* b2 = (const float*)d_in[7];
    const float* W3 = (const float*)d_in[8];
    const float* b3 = (const float*)d_in[9];
    const float* W4 = (const float*)d_in[10];
    const float* b4 = (const float*)d_in[11];
    float* out = (float*)d_out;
    f16* wt = (f16*)d_ws;                        // 3*128*128 f16 = 96 KB

    const int n_nodes = in_sizes[2] / 512;       // E*D / (16*32)
    const int nchunks = (n_nodes + CHUNK - 1) / CHUNK;
    const int blocks  = PBLOCKS < nchunks ? PBLOCKS : nchunks;

    prep_weights<<<(3 * 128 * 128 + 255) / 256, 256, 0, stream>>>(W1, W2, W3, wt);

    gnn_persist<<<blocks, NTHREADS, 0, stream>>>(
        edge_attr, wt, b1, b2, b3, W4, b4, out, n_nodes, nchunks);
}

// Round 12
// 207.720 us; speedup vs baseline: 1.0749x; 1.0749x over previous
//
#include <hip/hip_runtime.h>
#include <hip/hip_bf16.h>
#include <math.h>

// GNNAngle round 12: fully wave-autonomous. Each WAVE owns 16 nodes end-to-end
// in a private 4.25KB LDS tile: load -> Gram MFMA -> acos -> feats -> 3 MFMA
// MLP layers (B-frags held in regs, weights streamed from L2) -> final dot.
// ZERO __syncthreads. Cross-lane LDS handoffs inside a wave use explicit
// lgkmcnt(0) + sched_barrier (R6-proven). 128-thr blocks = 2 independent
// waves; ~18 free-running waves/CU. Attacks the 31%/31%/4% utilization profile
// (R11 counters) = lockstep/barrier-drain bound.

#define NTHREADS 128
#define ASTRIDE  136    // f16 row stride of the wave tile

typedef _Float16 f16;
typedef f16  f16x8 __attribute__((ext_vector_type(8)));
typedef f16  f16x4 __attribute__((ext_vector_type(4)));
typedef float f32x4 __attribute__((ext_vector_type(4)));

__device__ __forceinline__ float fast_tanh(float x) {
    float e = __expf(2.0f * x);
    return 1.0f - 2.0f * __builtin_amdgcn_rcpf(e + 1.0f);
}

__device__ __forceinline__ float fast_acos(float x) {
    // Abramowitz-Stegun 4.4.45: max abs error 6.7e-5 rad, branchless
    float ax = fabsf(x);
    float p = fmaf(-0.0187293f, ax, 0.0742610f);
    p = fmaf(p, ax, -0.2121144f);
    p = fmaf(p, ax, 1.5707288f);
    float r = sqrtf(1.0f - ax) * p;
    return (x >= 0.0f) ? r : (3.14159265358979f - r);
}

__device__ __forceinline__ void lgkm_fence() {
    asm volatile("s_waitcnt lgkmcnt(0)" ::: "memory");
    __builtin_amdgcn_sched_barrier(0);
}

// ---- prep: W[i][j] (f32 [IN][128]) -> Wt[j][i] f16 [128][128], K zero-padded
__global__ void prep_weights(const float* __restrict__ W1,
                             const float* __restrict__ W2,
                             const float* __restrict__ W3,
                             f16* __restrict__ wt)
{
    int tid = blockIdx.x * 256 + threadIdx.x;
    if (tid >= 3 * 128 * 128) return;
    int layer = tid >> 14;
    int rem   = tid & 16383;
    int j     = rem >> 7;
    int i     = rem & 127;
    const float* W = (layer == 0) ? W1 : ((layer == 1) ? W2 : W3);
    int in_l = (layer == 0) ? 120 : 128;
    float v = (i < in_l) ? W[i * 128 + j] : 0.0f;
    wt[tid] = (f16)v;   // wt[layer][j][i]
}

// per-node Gram+acos: c0/c1 = row lr, dims lg*8..+8; angles -> buf row m
__device__ __forceinline__ void gram_acos_node(float4 c0, float4 c1, int m,
                                               int lr, int lg, f16* buf)
{
    float ss = c0.x*c0.x + c0.y*c0.y + c0.z*c0.z + c0.w*c0.w
             + c1.x*c1.x + c1.y*c1.y + c1.z*c1.z + c1.w*c1.w;
    ss += __shfl_xor(ss, 16);
    ss += __shfl_xor(ss, 32);
    const float sc = __builtin_amdgcn_rsqf(ss + 1e-24f);
    f16x8 frag;
    frag[0] = (f16)(c0.x * sc); frag[1] = (f16)(c0.y * sc);
    frag[2] = (f16)(c0.z * sc); frag[3] = (f16)(c0.w * sc);
    frag[4] = (f16)(c1.x * sc); frag[5] = (f16)(c1.y * sc);
    frag[6] = (f16)(c1.z * sc); frag[7] = (f16)(c1.w * sc);
    f32x4 acc = {0.f, 0.f, 0.f, 0.f};
    acc = __builtin_amdgcn_mfma_f32_16x16x32_f16(frag, frag, acc, 0, 0, 0);
    const int col = lr;
    #pragma unroll
    for (int r2 = 0; r2 < 4; ++r2) {
        const int row = lg * 4 + r2;
        float c = fminf(fmaxf(acc[r2], -1.0f + 1e-7f), 1.0f - 1e-7f);
        float ang = fast_acos(c);
        if (row < col) {
            const int p = 15 * row - ((row * (row - 1)) >> 1) + (col - row - 1);
            buf[m * ASTRIDE + p] = (f16)ang;
        }
    }
}

// one MLP layer for the wave's 16-node tile, no barriers:
// buf[node][i] -> buf[node][j] = tanh(sum_i buf[node][i]*W[j][i] + b[j])
__device__ __forceinline__ void mlp_layer_wave(const f16* __restrict__ wl,   // [128][128] f16 ([j][i])
                                               const float* __restrict__ bias,
                                               f16* buf, int lr, int lg)
{
    lgkm_fence();   // prior writes (feats / previous layer) visible wave-wide
    const f16* sr = buf + lr * ASTRIDE + lg * 8;
    f16x8 bf0 = *(const f16x8*)(sr);
    f16x8 bf1 = *(const f16x8*)(sr + 32);
    f16x8 bf2 = *(const f16x8*)(sr + 64);
    f16x8 bf3 = *(const f16x8*)(sr + 96);
    lgkm_fence();   // bf in regs before any jt write below touches buf
    #pragma unroll
    for (int jt = 0; jt < 8; ++jt) {
        const f16* wr = wl + (jt * 16 + lr) * 128 + lg * 8;
        f16x8 a0 = *(const f16x8*)(wr);
        f16x8 a1 = *(const f16x8*)(wr + 32);
        f16x8 a2 = *(const f16x8*)(wr + 64);
        f16x8 a3 = *(const f16x8*)(wr + 96);
        f32x4 bv = *(const f32x4*)(bias + jt * 16 + lg * 4);
        f32x4 acc = {0.f, 0.f, 0.f, 0.f};
        acc = __builtin_amdgcn_mfma_f32_16x16x32_f16(a0, bf0, acc, 0, 0, 0);
        acc = __builtin_amdgcn_mfma_f32_16x16x32_f16(a1, bf1, acc, 0, 0, 0);
        acc = __builtin_amdgcn_mfma_f32_16x16x32_f16(a2, bf2, acc, 0, 0, 0);
        acc = __builtin_amdgcn_mfma_f32_16x16x32_f16(a3, bf3, acc, 0, 0, 0);
        f16x4 o;
        #pragma unroll
        for (int r = 0; r < 4; ++r)
            o[r] = (f16)fast_tanh(acc[r] + bv[r]);
        // D: col=lane&15=node(lr), rows j=jt*16+lg*4+r
        *(f16x4*)(buf + lr * ASTRIDE + jt * 16 + lg * 4) = o;
    }
}

__global__ __launch_bounds__(NTHREADS, 3)
void gnn_wave(const float* __restrict__ edge_attr,
              const f16*   __restrict__ wt,     // 3x[128][128] f16
              const float* __restrict__ b1, const float* __restrict__ b2,
              const float* __restrict__ b3,
              const float* __restrict__ W4, const float* __restrict__ b4,
              float* __restrict__ out, int n_nodes)
{
    __shared__ __attribute__((aligned(16))) f16 bufs[2][16 * ASTRIDE];  // 8.5 KB

    const int t  = threadIdx.x;
    const int w  = t >> 6;     // wave 0/1 — fully independent
    const int l  = t & 63;
    const int lr = l & 15;
    const int lg = l >> 4;
    f16* buf = bufs[w];
    const long gbase = (long)blockIdx.x * 32 + (long)w * 16;

    // zero K-pad cols 120..127 of all 16 rows (layer-1 input padding)
    buf[(l >> 3) * ASTRIDE + 120 + (l & 7)]       = (f16)0.f;
    buf[((l >> 3) + 8) * ASTRIDE + 120 + (l & 7)] = (f16)0.f;

    // ---- phase A: 16 nodes, 4-node batches, 2-deep load pipeline ----
    const float* sw = edge_attr + gbase * 512 + lr * 32 + lg * 8;
    #define LOADB(va, vb, m)                                          \
        {                                                             \
            const long gn = gbase + (m);                              \
            va = make_float4(0.f, 0.f, 0.f, 0.f); vb = va;            \
            if (gn < n_nodes) {                                       \
                const float* s = sw + (long)(m) * 512;                \
                va = *(const float4*)(s);                             \
                vb = *(const float4*)(s + 4);                         \
            }                                                         \
        }
    float4 c0a,c0b,c1a,c1b,c2a,c2b,c3a,c3b;
    LOADB(c0a,c0b,0) LOADB(c1a,c1b,1) LOADB(c2a,c2b,2) LOADB(c3a,c3b,3)
    #pragma unroll
    for (int bt = 0; bt < 4; ++bt) {
        float4 n0a,n0b,n1a,n1b,n2a,n2b,n3a,n3b;
        if (bt < 3) {
            LOADB(n0a,n0b,bt*4+4) LOADB(n1a,n1b,bt*4+5)
            LOADB(n2a,n2b,bt*4+6) LOADB(n3a,n3b,bt*4+7)
        }
        gram_acos_node(c0a, c0b, bt*4+0, lr, lg, buf);
        gram_acos_node(c1a, c1b, bt*4+1, lr, lg, buf);
        gram_acos_node(c2a, c2b, bt*4+2, lr, lg, buf);
        gram_acos_node(c3a, c3b, bt*4+3, lr, lg, buf);
        if (bt < 3) {
            c0a=n0a; c0b=n0b; c1a=n1a; c1b=n1b;
            c2a=n2a; c2b=n2b; c3a=n3a; c3b=n3b;
        }
    }
    #undef LOADB

    // ---- phase B: 3 MFMA MLP layers, wave-private, no barriers ----
    mlp_layer_wave(wt,             b1, buf, lr, lg);
    mlp_layer_wave(wt + 16384,     b2, buf, lr, lg);
    mlp_layer_wave(wt + 2 * 16384, b3, buf, lr, lg);

    // ---- final 128->1 + sigmoid: 4 lanes per node ----
    lgkm_fence();
    {
        const int fp = lg;                     // part 0..3 (32 inputs each)
        const f16* fs = buf + lr * ASTRIDE + fp * 32;
        f16x8 h0 = *(const f16x8*)(fs);
        f16x8 h1 = *(const f16x8*)(fs + 8);
        f16x8 h2 = *(const f16x8*)(fs + 16);
        f16x8 h3 = *(const f16x8*)(fs + 24);
        const float* wp = W4 + fp * 32;
        float s = 0.f;
        #pragma unroll
        for (int e = 0; e < 8; ++e) s = fmaf((float)h0[e], wp[e],      s);
        #pragma unroll
        for (int e = 0; e < 8; ++e) s = fmaf((float)h1[e], wp[e + 8],  s);
        #pragma unroll
        for (int e = 0; e < 8; ++e) s = fmaf((float)h2[e], wp[e + 16], s);
        #pragma unroll
        for (int e = 0; e < 8; ++e) s = fmaf((float)h3[e], wp[e + 24], s);
        s += __shfl_xor(s, 16);
        s += __shfl_xor(s, 32);                // sum the 4 parts of node lr
        if (lg == 0) {
            const long g = gbase + lr;
            if (g < n_nodes)
                out[g] = __builtin_amdgcn_rcpf(1.0f + __expf(-(s + b4[0])));
        }
    }
}

extern "C" void kernel_launch(void* const* d_in, const int* in_sizes, int n_in,
                              void* d_out, int out_size, void* d_ws, size_t ws_size,
                              hipStream_t stream) {
    // inputs: 0:x 1:edge_index 2:edge_attr 3:k 4:W1 5:b1 6:W2 7:b2 8:W3 9:b3 10:W4 11:b4
    const float* edge_attr = (const float*)d_in[2];
    const float* W1 = (const float*)d_in[4];
    const float* b1 = (const float*)d_in[5];
    const float* W2 = (const float*)d_in[6];
    const float* b2 = (const float*)d_in[7];
    const float* W3 = (const float*)d_in[8];
    const float* b3 = (const float*)d_in[9];
    const float* W4 = (const float*)d_in[10];
    const float* b4 = (const float*)d_in[11];
    float* out = (float*)d_out;
    f16* wt = (f16*)d_ws;                        // 3*128*128 f16 = 96 KB

    const int n_nodes = in_sizes[2] / 512;       // E*D / (16*32)

    prep_weights<<<(3 * 128 * 128 + 255) / 256, 256, 0, stream>>>(W1, W2, W3, wt);

    const int blocks = (n_nodes + 31) / 32;      // 32 nodes per 128-thr block
    gnn_wave<<<blocks, NTHREADS, 0, stream>>>(
        edge_attr, wt, b1, b2, b3, W4, b4, out, n_nodes);
}

// Round 13
// 138.293 us; speedup vs baseline: 1.6145x; 1.5020x over previous
//
#include <hip/hip_runtime.h>
#include <hip/hip_bf16.h>
#include <math.h>

// GNNAngle round 13: kill phase A's serial per-node chain (R11/R12 counters:
// all pipes ~2/3 idle => dependency-latency bound). Compute UNNORMALIZED Gram
// G=V*V^T straight from raw f16 (load->cvt->MFMA, no shfl preamble), then
// cos[i][j] = G[i][j]*rsq(G[ii])*rsq(G[jj]) via a per-wave diag LDS array:
// 16 lanes write rsq(diag), ONE fence for all 8 nodes, 2 reads/lane/node.
// All 8 node-chains independent => compiler can interleave. MLP = R9.

#define NTHREADS 256    // 4 waves
#define CHUNK    32     // nodes per block
#define ASTRIDE  136    // f16 act row stride (b128 conflict-free in MLP)

typedef _Float16 f16;
typedef f16  f16x8 __attribute__((ext_vector_type(8)));
typedef f16  f16x4 __attribute__((ext_vector_type(4)));
typedef float f32x4 __attribute__((ext_vector_type(4)));

__device__ __forceinline__ float fast_tanh(float x) {
    float e = __expf(2.0f * x);
    return 1.0f - 2.0f * __builtin_amdgcn_rcpf(e + 1.0f);
}

__device__ __forceinline__ float fast_acos(float x) {
    // Abramowitz-Stegun 4.4.45: max abs error 6.7e-5 rad, branchless
    float ax = fabsf(x);
    float p = fmaf(-0.0187293f, ax, 0.0742610f);
    p = fmaf(p, ax, -0.2121144f);
    p = fmaf(p, ax, 1.5707288f);
    float r = sqrtf(1.0f - ax) * p;
    return (x >= 0.0f) ? r : (3.14159265358979f - r);
}

// ---- prep: W[i][j] (f32 [IN][128]) -> Wt[j][i] f16 [128][128], K zero-padded
__global__ void prep_weights(const float* __restrict__ W1,
                             const float* __restrict__ W2,
                             const float* __restrict__ W3,
                             f16* __restrict__ wt)
{
    int tid = blockIdx.x * 256 + threadIdx.x;
    if (tid >= 3 * 128 * 128) return;
    int layer = tid >> 14;
    int rem   = tid & 16383;
    int j     = rem >> 7;
    int i     = rem & 127;
    const float* W = (layer == 0) ? W1 : ((layer == 1) ? W2 : W3);
    int in_l = (layer == 0) ? 120 : 128;
    float v = (i < in_l) ? W[i * 128 + j] : 0.0f;
    wt[tid] = (f16)v;   // wt[layer][j][i]
}

// one MLP layer: dst[node][j] = tanh(sum_i src[node][i]*W[i][j] + b[j])
__device__ __forceinline__ void mlp_layer_mfma(const f16* __restrict__ wl,   // [128][128] f16 ([j][i])
                                               const float* __restrict__ bias,
                                               const f16* src, f16* dst,     // LDS, stride ASTRIDE
                                               int w, int lr, int lg)
{
    #pragma unroll
    for (int jj = 0; jj < 2; ++jj) {
        const int jt = w * 2 + jj;
        const f16* wr = wl + (jt * 16 + lr) * 128 + lg * 8;
        f16x8 a0 = *(const f16x8*)(wr);
        f16x8 a1 = *(const f16x8*)(wr + 32);
        f16x8 a2 = *(const f16x8*)(wr + 64);
        f16x8 a3 = *(const f16x8*)(wr + 96);
        f32x4 bv = *(const f32x4*)(bias + jt * 16 + lg * 4);
        #pragma unroll
        for (int nt = 0; nt < 2; ++nt) {
            const int node = nt * 16 + lr;
            const f16* sr = src + node * ASTRIDE + lg * 8;
            f16x8 bf0 = *(const f16x8*)(sr);
            f16x8 bf1 = *(const f16x8*)(sr + 32);
            f16x8 bf2 = *(const f16x8*)(sr + 64);
            f16x8 bf3 = *(const f16x8*)(sr + 96);
            f32x4 acc = {0.f, 0.f, 0.f, 0.f};
            acc = __builtin_amdgcn_mfma_f32_16x16x32_f16(a0, bf0, acc, 0, 0, 0);
            acc = __builtin_amdgcn_mfma_f32_16x16x32_f16(a1, bf1, acc, 0, 0, 0);
            acc = __builtin_amdgcn_mfma_f32_16x16x32_f16(a2, bf2, acc, 0, 0, 0);
            acc = __builtin_amdgcn_mfma_f32_16x16x32_f16(a3, bf3, acc, 0, 0, 0);
            f16x4 o;
            #pragma unroll
            for (int r = 0; r < 4; ++r)
                o[r] = (f16)fast_tanh(acc[r] + bv[r]);
            *(f16x4*)(dst + node * ASTRIDE + jt * 16 + lg * 4) = o;
        }
    }
}

__global__ __launch_bounds__(NTHREADS, 3)
void gnn_angle_fused(const float* __restrict__ edge_attr,
                     const f16*   __restrict__ wt,     // 3x[128][128] f16
                     const float* __restrict__ b1, const float* __restrict__ b2,
                     const float* __restrict__ b3,
                     const float* __restrict__ W4, const float* __restrict__ b4,
                     float* __restrict__ out, int n_nodes)
{
    __shared__ __attribute__((aligned(16))) f16   actA[CHUNK * ASTRIDE];
    __shared__ __attribute__((aligned(16))) f16   actB[CHUNK * ASTRIDE];
    __shared__ __attribute__((aligned(16))) float diag[4][8][16];   // rsq of Gram diag, 2 KB

    const int t = threadIdx.x;
    const int w = t >> 6;    // wave 0..3
    const int l = t & 63;
    const int base = blockIdx.x * CHUNK;
    const int lr = l & 15;
    const int lg = l >> 4;

    // K-pad feats 120..127 for all 32 rows, once
    actA[(t >> 3) * ASTRIDE + 120 + (t & 7)] = (f16)0.f;

    // wave w owns nodes m = 4c + w, c = 0..7; lane holds row lr, dims lg*8..+8
    const float* sw = edge_attr + ((long)base + w) * 512 + lr * 32 + lg * 8;

    // ---- load all 8 nodes (16 x dwordx4 in flight) ----
    float4 d0a,d0b,d1a,d1b,d2a,d2b,d3a,d3b,d4a,d4b,d5a,d5b,d6a,d6b,d7a,d7b;
    if (base + CHUNK <= n_nodes) {
        d0a = *(const float4*)(sw +     0); d0b = *(const float4*)(sw +     4);
        d1a = *(const float4*)(sw +  2048); d1b = *(const float4*)(sw +  2052);
        d2a = *(const float4*)(sw +  4096); d2b = *(const float4*)(sw +  4100);
        d3a = *(const float4*)(sw +  6144); d3b = *(const float4*)(sw +  6148);
        d4a = *(const float4*)(sw +  8192); d4b = *(const float4*)(sw +  8196);
        d5a = *(const float4*)(sw + 10240); d5b = *(const float4*)(sw + 10244);
        d6a = *(const float4*)(sw + 12288); d6b = *(const float4*)(sw + 12292);
        d7a = *(const float4*)(sw + 14336); d7b = *(const float4*)(sw + 14340);
    } else {
        #define LOADG(da, db, c)                                           \
            da = make_float4(0.f,0.f,0.f,0.f); db = da;                    \
            if ((long)base + 4*(c) + w < n_nodes) {                        \
                da = *(const float4*)(sw + (c) * 2048);                    \
                db = *(const float4*)(sw + (c) * 2048 + 4);                \
            }
        LOADG(d0a,d0b,0) LOADG(d1a,d1b,1) LOADG(d2a,d2b,2) LOADG(d3a,d3b,3)
        LOADG(d4a,d4b,4) LOADG(d5a,d5b,5) LOADG(d6a,d6b,6) LOADG(d7a,d7b,7)
        #undef LOADG
        // invalid nodes: zeros -> G=0 -> cos=0 -> acos=pi/2 junk; out store guarded
    }

    // ---- cvt -> MFMA (independent per node, no cross-lane preamble) ----
    f32x4 g0,g1,g2,g3,g4,g5,g6,g7;
    #define GRAM(gc, da, db)                                               \
        {                                                                  \
            f16x8 fr;                                                      \
            fr[0]=(f16)da.x; fr[1]=(f16)da.y; fr[2]=(f16)da.z; fr[3]=(f16)da.w; \
            fr[4]=(f16)db.x; fr[5]=(f16)db.y; fr[6]=(f16)db.z; fr[7]=(f16)db.w; \
            f32x4 z = {0.f,0.f,0.f,0.f};                                   \
            gc = __builtin_amdgcn_mfma_f32_16x16x32_f16(fr, fr, z, 0,0,0); \
        }
    GRAM(g0,d0a,d0b) GRAM(g1,d1a,d1b) GRAM(g2,d2a,d2b) GRAM(g3,d3a,d3b)
    GRAM(g4,d4a,d4b) GRAM(g5,d5a,d5b) GRAM(g6,d6a,d6b) GRAM(g7,d7a,d7b)
    #undef GRAM

    // ---- 16 diag lanes write rsq(G[ii]); ONE fence for all 8 nodes ----
    // lane (lr,lg) holds D rows lg*4+r for col lr => diag element when lg==lr>>2, r=lr&3
    if (lg == (lr >> 2)) {
        const int r = lr & 3;
        diag[w][0][lr] = __builtin_amdgcn_rsqf(g0[r] + 1e-24f);
        diag[w][1][lr] = __builtin_amdgcn_rsqf(g1[r] + 1e-24f);
        diag[w][2][lr] = __builtin_amdgcn_rsqf(g2[r] + 1e-24f);
        diag[w][3][lr] = __builtin_amdgcn_rsqf(g3[r] + 1e-24f);
        diag[w][4][lr] = __builtin_amdgcn_rsqf(g4[r] + 1e-24f);
        diag[w][5][lr] = __builtin_amdgcn_rsqf(g5[r] + 1e-24f);
        diag[w][6][lr] = __builtin_amdgcn_rsqf(g6[r] + 1e-24f);
        diag[w][7][lr] = __builtin_amdgcn_rsqf(g7[r] + 1e-24f);
    }
    asm volatile("s_waitcnt lgkmcnt(0)" ::: "memory");
    __builtin_amdgcn_sched_barrier(0);

    // ---- normalize + acos + scatter (independent per node) ----
    #define FIN(gc, c)                                                     \
        {                                                                  \
            const float rc = diag[w][c][lr];                               \
            const f32x4 rr = *(const f32x4*)&diag[w][c][lg * 4];           \
            const int m = (c) * 4 + w;                                     \
            const int col = lr;                                            \
            _Pragma("unroll")                                              \
            for (int r2 = 0; r2 < 4; ++r2) {                               \
                const int row = lg * 4 + r2;                               \
                float cv = gc[r2] * rr[r2] * rc;                           \
                cv = fminf(fmaxf(cv, -1.0f + 1e-7f), 1.0f - 1e-7f);        \
                float ang = fast_acos(cv);                                 \
                if (row < col) {                                           \
                    const int p = 15*row - ((row*(row-1))>>1) + (col-row-1); \
                    actA[m * ASTRIDE + p] = (f16)ang;                      \
                }                                                          \
            }                                                              \
        }
    FIN(g0,0) FIN(g1,1) FIN(g2,2) FIN(g3,3)
    FIN(g4,4) FIN(g5,5) FIN(g6,6) FIN(g7,7)
    #undef FIN
    __syncthreads();

    // ---------------- Phase B: MLP on MFMA ----------------
    mlp_layer_mfma(wt,             b1, actA, actB, w, lr, lg);
    __syncthreads();
    mlp_layer_mfma(wt + 16384,     b2, actB, actA, w, lr, lg);
    __syncthreads();
    mlp_layer_mfma(wt + 2 * 16384, b3, actA, actB, w, lr, lg);
    __syncthreads();

    // ---------------- final 128->1 + sigmoid: 8 threads per node ----------------
    {
        const int node = t >> 3;       // 0..31
        const int part = t & 7;        // 0..7
        const int i0 = part * 16;
        const f16* sr = actB + node * ASTRIDE + i0;
        f16x8 h0 = *(const f16x8*)(sr);
        f16x8 h1 = *(const f16x8*)(sr + 8);
        float s = 0.f;
        #pragma unroll
        for (int e = 0; e < 8; ++e) s = fmaf((float)h0[e], W4[i0 + e], s);
        #pragma unroll
        for (int e = 0; e < 8; ++e) s = fmaf((float)h1[e], W4[i0 + 8 + e], s);
        s += __shfl_xor(s, 1);
        s += __shfl_xor(s, 2);
        s += __shfl_xor(s, 4);
        if (part == 0) {
            const long g = (long)base + node;
            if (g < n_nodes)
                out[g] = __builtin_amdgcn_rcpf(1.0f + __expf(-(s + b4[0])));
        }
    }
}

extern "C" void kernel_launch(void* const* d_in, const int* in_sizes, int n_in,
                              void* d_out, int out_size, void* d_ws, size_t ws_size,
                              hipStream_t stream) {
    // inputs: 0:x 1:edge_index 2:edge_attr 3:k 4:W1 5:b1 6:W2 7:b2 8:W3 9:b3 10:W4 11:b4
    const float* edge_attr = (const float*)d_in[2];
    const float* W1 = (const float*)d_in[4];
    const float* b1 = (const float*)d_in[5];
    const float* W2 = (const float*)d_in[6];
    const float* b2 = (const float*)d_in[7];
    const float* W3 = (const float*)d_in[8];
    const float* b3 = (const float*)d_in[9];
    const float* W4 = (const float*)d_in[10];
    const float* b4 = (const float*)d_in[11];
    float* out = (float*)d_out;
    f16* wt = (f16*)d_ws;                        // 3*128*128 f16 = 96 KB

    const int n_nodes = in_sizes[2] / 512;       // E*D / (16*32)

    prep_weights<<<(3 * 128 * 128 + 255) / 256, 256, 0, stream>>>(W1, W2, W3, wt);

    const int blocks = (n_nodes + CHUNK - 1) / CHUNK;
    gnn_angle_fused<<<blocks, NTHREADS, 0, stream>>>(
        edge_attr, wt, b1, b2, b3, W4, b4, out, n_nodes);
}